// Round 9
// baseline (243.807 us; speedup 1.0000x reference)
//
#include <hip/hip_runtime.h>
#include <math.h>

#define NN 25000
#define NE 400000
#define TD 416
#define TCAP 46080             // per-type bucket capacity (64-aligned, mean 40000 + 7.8 sigma)
#define NROWS (TCAP * 10)      // 460800 bucket slots
#define PLH 64                 // payload row stride in halves (128 B = 2 lines)
#define NCAP 64                // fixed payload rows per node (deg ~Poisson(16); P(>=64) ~ 1e-20)
#define BPT (TCAP / 64)        // 720 one-wave blocks per type

typedef __attribute__((ext_vector_type(8))) __bf16 bf16x8;
typedef __attribute__((ext_vector_type(4))) _Float16 f16x4;
typedef __attribute__((ext_vector_type(4))) float f32x4;

__device__ __forceinline__ float silu_f(float x) {
    // fast rcp: v_rcp_f32 (1 inst) instead of IEEE div sequence (~11 insts).
    return x * __builtin_amdgcn_rcpf(1.0f + __expf(-x));
}

// ---------- fused: [blocks 0..63] weight prep, [blocks 64..] count + geometry + bucket ----------
// Geometry computed HERE where e is linear (edst/esrc/shifts streamed; pos gathers are
// L2-resident 300KB). Bucket record = {vx,vy,vz, pd} so edge_k has zero random gathers.
__global__ __launch_bounds__(256) void prep_count_k(
    const float* __restrict__ emb_table,
    const float* __restrict__ aw1, const float* __restrict__ ab1,
    const float* __restrict__ aw2, const float* __restrict__ ab2,
    const float* __restrict__ fw1, const float* __restrict__ fb1,
    const float* __restrict__ fw2,
    const float* __restrict__ fw3, const float* __restrict__ fb3,
    __bf16* __restrict__ w1a, __bf16* __restrict__ w2a,
    __bf16* __restrict__ w3ta, float* __restrict__ b3t,
    const int* __restrict__ esrc, const int* __restrict__ edst,
    const int* __restrict__ A,
    const float* __restrict__ pos, const float* __restrict__ shifts,
    const float* __restrict__ cell, const int* __restrict__ batch,
    int* __restrict__ cnt_dst, int* __restrict__ cnt_t,
    int4* __restrict__ tlist4) {
    const int tid = threadIdx.x;
    if (blockIdx.x < 64) {
        __shared__ float s_ai[80];
        if (tid < 10) {
            float acc[8];
#pragma unroll
            for (int o = 0; o < 8; ++o) acc[o] = ab2[o];
            for (int j = 0; j < 64; ++j) {
                float h = ab1[j];
#pragma unroll
                for (int i = 0; i < 16; ++i) h += emb_table[tid * 16 + i] * aw1[i * 64 + j];
                h = silu_f(h);
#pragma unroll
                for (int o = 0; o < 8; ++o) acc[o] += h * aw2[j * 8 + o];
            }
#pragma unroll
            for (int o = 0; o < 8; ++o) s_ai[tid * 8 + o] = acc[o];
        }
        __syncthreads();
        for (int i = blockIdx.x * 256 + tid; i < 37344; i += 64 * 256) {
            if (i < 2048) {
                int m = i >> 9, r = i & 511, lane = r >> 3, j = r & 7;
                int k = (lane >> 4) * 8 + j, ch = m * 16 + (lane & 15);
                float v = (k < 8) ? fw1[k * 64 + ch] : ((k == 8) ? fb1[ch] : 0.0f);
                w1a[i] = (__bf16)v;
            } else if (i < 6144) {
                int q = i - 2048;
                int mk = q >> 9, lane = (q >> 3) & 63, j = q & 7;
                int m = mk >> 1, kt = mk & 1;
                int k = kt * 32 + (lane >> 4) * 8 + j, ch = m * 16 + (lane & 15);
                w2a[q] = (__bf16)fw2[k * 64 + ch];
            } else if (i < 36864) {
                int q = i - 6144;
                int tmk = q >> 9, lane = (q >> 3) & 63, j = q & 7;
                int kt = tmk & 1, tm = tmk >> 1;
                int t = tm / 3, m = tm - t * 3;
                int k = kt * 32 + (lane >> 4) * 8 + j, ch = m * 16 + (lane & 15);
                int l = ch >> 4, o = ch & 15;
                float s = 0.f;
#pragma unroll
                for (int c = 0; c < 8; ++c)
                    s += s_ai[t * 8 + c] * fw3[k * 384 + l * 128 + c * 16 + o];
                w3ta[q] = (__bf16)s;
            } else {
                int q2 = i - 36864;
                int t = q2 / 48, ch = q2 - t * 48;
                int l = ch >> 4, o = ch & 15;
                float s = 0.f;
#pragma unroll
                for (int c = 0; c < 8; ++c)
                    s += s_ai[t * 8 + c] * fb3[l * 128 + c * 16 + o];
                b3t[q2] = s;
            }
        }
    } else {
        __shared__ int lcnt[10];
        __shared__ int gbase[10];
        if (tid < 10) lcnt[tid] = 0;
        __syncthreads();
        int e = (blockIdx.x - 64) * 256 + tid;
        int t = 0, lr = 0;
        int4 rec;
        bool valid = e < NE;
        if (valid) {
            const int dst = edst[e];                     // linear
            const int src = esrc[e];                     // linear
            int rank = atomicAdd(&cnt_dst[dst], 1);      // rank within dst node (< NCAP)
            t = A[src];
            lr = atomicAdd(&lcnt[t], 1);
            // geometry (shifts linear; pos gathers hit L2: 300KB array)
            const int b = batch[src];
            const float* cb = cell + b * 9;
            const float sh0 = shifts[e * 3 + 0], sh1 = shifts[e * 3 + 1], sh2 = shifts[e * 3 + 2];
            float vx = pos[dst * 3 + 0] - pos[src * 3 + 0] + sh0 * cb[0] + sh1 * cb[3] + sh2 * cb[6];
            float vy = pos[dst * 3 + 1] - pos[src * 3 + 1] + sh0 * cb[1] + sh1 * cb[4] + sh2 * cb[7];
            float vz = pos[dst * 3 + 2] - pos[src * 3 + 2] + sh0 * cb[2] + sh1 * cb[5] + sh2 * cb[8];
            rec.x = __float_as_int(vx);
            rec.y = __float_as_int(vy);
            rec.z = __float_as_int(vz);
            rec.w = (dst << 6) | rank;                   // pd = dst*NCAP + rank
        }
        __syncthreads();
        if (tid < 10) gbase[tid] = atomicAdd(&cnt_t[tid], lcnt[tid]);
        __syncthreads();
        if (valid) tlist4[t * TCAP + gbase[t] + lr] = rec;
    }
}

// ---------- edge kernel: 1 wave = 64 edges; 3 MFMA GEMMs; single streamed 16B input ----------
// Zero random gathers: the bucket record carries vec + payload row. Weights register-resident.
// 1-wave WGs: __syncthreads compiles to bare waitcnts (verified optimum vs r6/r7/r8 variants).
__global__ __launch_bounds__(64) void edge_k(
    const int4* __restrict__ tlist4, const int* __restrict__ cnt_t,
    const __bf16* __restrict__ w1a, const __bf16* __restrict__ w2a,
    const __bf16* __restrict__ w3ta,
    const float* __restrict__ fb2, const float* __restrict__ b3t,
    _Float16* __restrict__ payload) {
    __shared__ __bf16 embuf[64 * 8];                   // 1 KB (8 real basis values/edge)
    __shared__ __bf16 h1buf[16 * 72];                  // 2.3 KB
    __shared__ __bf16 h2buf[16 * 72];                  // 2.3 KB
    __shared__ int pbuf[64];                           // payload row index per wave slot
    const int lane = threadIdx.x;
    const int t_blk = blockIdx.x / BPT;
    const int local = (blockIdx.x - t_blk * BPT) * 64;
    const int nval = cnt_t[t_blk];
    if (local >= nval) return;                         // fully-padded block

    const int idx = min(local + lane, nval - 1);       // pad lanes dup last edge (benign)
    const int4 rec = tlist4[t_blk * TCAP + idx];       // ONE streamed 16B load = whole input
    const float vx = __int_as_float(rec.x);
    const float vy = __int_as_float(rec.y);
    const float vz = __int_as_float(rec.z);
    const int pd = rec.w;
    pbuf[lane] = pd;

    const float l2 = vx * vx + vy * vy + vz * vz + 1e-12f;
    const float il = __builtin_amdgcn_rsqf(l2);        // v_rsq_f32
    const float len = l2 * il;
    // u + zero pad -> bytes 96..127 of the row fully written (no RMW fetch)
    {
        const uint4 z4 = {0u, 0u, 0u, 0u};
        union { float f[4]; uint4 u; } uu;
        uu.f[0] = vx * il; uu.f[1] = vy * il; uu.f[2] = vz * il; uu.f[3] = 0.f;
        *(uint4*)(payload + (size_t)pd * PLH + 48) = uu.u;
        *(uint4*)(payload + (size_t)pd * PLH + 56) = z4;
    }

    // radial basis row (8 real values; constant rows handled in-register via bone)
    bf16x8 er0;
#pragma unroll
    for (int k = 0; k < 8; ++k) {
        float d = (len - (5.0f * (float)(k + 1) / 9.0f)) * 1.8f;
        er0[k] = (__bf16)(__expf(-d * d) * 2.525381361380528f);  // sqrt(8)/1.12
    }
    *(bf16x8*)&embuf[lane * 8] = er0;

    // ---- weights + biases: block-resident in VGPRs ----
    bf16x8 a1[4], a2[8], a3[6];
#pragma unroll
    for (int m = 0; m < 4; ++m) a1[m] = *(const bf16x8*)(w1a + (m * 64 + lane) * 8);
#pragma unroll
    for (int i = 0; i < 8; ++i) a2[i] = *(const bf16x8*)(w2a + (i * 64 + lane) * 8);
#pragma unroll
    for (int i = 0; i < 6; ++i)
        a3[i] = *(const bf16x8*)(w3ta + ((size_t)(t_blk * 6 + i) * 64 + lane) * 8);
    const int q = lane >> 4;
    const int qr = q * 4;
    const int q8 = q * 8;
    const int colrow = lane & 15;
    f32x4 bias2[4], bias3[3];
#pragma unroll
    for (int m = 0; m < 4; ++m) bias2[m] = *(const f32x4*)(fb2 + m * 16 + qr);
#pragma unroll
    for (int m = 0; m < 3; ++m) bias3[m] = *(const f32x4*)(b3t + t_blk * 48 + m * 16 + qr);

    bf16x8 bone = {};
    bone[0] = (__bf16)1.0f;   // k=8 bias row; k>8 rows multiply zero weights
    __syncthreads();          // covers embuf + pbuf

    const float SC = (float)NN / (float)NE;  // 1/16
#pragma unroll 1
    for (int n = 0; n < 4; ++n) {
        const int erow = n * 16 + colrow;
        // GEMM1: h1 = silu(emb @ W1 + b1); B-quadrants 1..3 are constants
        bf16x8 bd = *(bf16x8*)&embuf[erow * 8];
        bf16x8 b1 = (q == 0) ? bd : bone;
#pragma unroll
        for (int m = 0; m < 4; ++m) {
            f32x4 c = {0.f, 0.f, 0.f, 0.f};
            c = __builtin_amdgcn_mfma_f32_16x16x32_bf16(a1[m], b1, c, 0, 0, 0);
            __bf16 hp[4];
#pragma unroll
            for (int r = 0; r < 4; ++r) hp[r] = (__bf16)silu_f(c[r]);
            *(uint2*)&h1buf[colrow * 72 + m * 16 + qr] = *(uint2*)hp;
        }
        __syncthreads();
        // GEMM2: h2 = silu(h1 @ W2 + b2)
        bf16x8 b20 = *(bf16x8*)&h1buf[colrow * 72 + q8];
        bf16x8 b21 = *(bf16x8*)&h1buf[colrow * 72 + 32 + q8];
#pragma unroll
        for (int m = 0; m < 4; ++m) {
            f32x4 c = bias2[m];
            c = __builtin_amdgcn_mfma_f32_16x16x32_bf16(a2[m * 2 + 0], b20, c, 0, 0, 0);
            c = __builtin_amdgcn_mfma_f32_16x16x32_bf16(a2[m * 2 + 1], b21, c, 0, 0, 0);
            __bf16 hp[4];
#pragma unroll
            for (int r = 0; r < 4; ++r) hp[r] = (__bf16)silu_f(c[r]);
            *(uint2*)&h2buf[colrow * 72 + m * 16 + qr] = *(uint2*)hp;
        }
        __syncthreads();
        // GEMM3: s = (h2 @ W3t + b3t) * SC -> fp16 straight to global payload row
        const int prow = pbuf[erow];
        bf16x8 b30 = *(bf16x8*)&h2buf[colrow * 72 + q8];
        bf16x8 b31 = *(bf16x8*)&h2buf[colrow * 72 + 32 + q8];
#pragma unroll
        for (int m = 0; m < 3; ++m) {
            f32x4 c = bias3[m];
            c = __builtin_amdgcn_mfma_f32_16x16x32_bf16(a3[m * 2 + 0], b30, c, 0, 0, 0);
            c = __builtin_amdgcn_mfma_f32_16x16x32_bf16(a3[m * 2 + 1], b31, c, 0, 0, 0);
            f16x4 hp;
#pragma unroll
            for (int r = 0; r < 4; ++r) hp[r] = (_Float16)(c[r] * SC);
            *(f16x4*)(payload + (size_t)prow * PLH + m * 16 + qr) = hp;
        }
        // no barrier: next iter's h1buf write is fenced by the GEMM1-end barrier,
        // whose lgkmcnt(0) drain also retires this iter's h2buf reads.
    }
}

// ---------- gather: direct-read, LDS-free, barrier-free ----------
// Node rows are contiguous and L1-resident once touched: each of the 208 lanes reads
// its own fp16 value (lanes span <=2 lines -> coalesced) + 3 broadcast u floats per row,
// computes wa*wb via cndmask chains, accumulates in-register. Zero LDS, zero barriers;
// the unrolled r-loop keeps ~16 independent loads in flight.
__global__ __launch_bounds__(256) void gather_k(const int* __restrict__ cnt_dst,
                                                const _Float16* __restrict__ payload,
                                                float* __restrict__ out) {
    const int n = blockIdx.x;
    const int tid = threadIdx.x;
    if (tid >= 208) return;
    const int cnt = cnt_dst[n];
    const _Float16* base = payload + (size_t)n * NCAP * PLH;

    int voff, ia, ib;
    if (tid < 16) { voff = tid; ia = 0; ib = 0; }
    else if (tid < 64) { int q = tid - 16; voff = 16 + q / 3; ia = 1 + q % 3; ib = 0; }
    else { int q = tid - 64; voff = 32 + q / 9; int g = q % 9; ia = 1 + g / 3; ib = 1 + g % 3; }

    float acc = 0.f;
#pragma unroll 4
    for (int r = 0; r < cnt; ++r) {
        const _Float16* row = base + r * PLH;
        const float v = (float)row[voff];
        const float* uf = (const float*)(row + 48);
        const float u0 = uf[0], u1 = uf[1], u2 = uf[2];      // broadcast L1 hits
        const float wa = (ia == 0) ? 1.f : ((ia == 1) ? u0 : ((ia == 2) ? u1 : u2));
        const float wb = (ib == 0) ? 1.f : ((ib == 1) ? u0 : ((ib == 2) ? u1 : u2));
        acc += v * (wa * wb);
    }
    out[(size_t)n * TD + tid] = acc;
    out[(size_t)n * TD + 208 + tid] = 0.f;
}

extern "C" void kernel_launch(void* const* d_in, const int* in_sizes, int n_in,
                              void* d_out, int out_size, void* d_ws, size_t ws_size,
                              hipStream_t stream) {
    const float* pos       = (const float*)d_in[0];
    const int*   A         = (const int*)d_in[1];
    const int*   batch     = (const int*)d_in[2];
    const int*   esrc      = (const int*)d_in[3];
    const int*   edst      = (const int*)d_in[4];
    const float* shifts    = (const float*)d_in[5];
    const float* cell      = (const float*)d_in[6];
    const float* emb_table = (const float*)d_in[7];
    const float* aw1       = (const float*)d_in[8];
    const float* ab1       = (const float*)d_in[9];
    const float* aw2       = (const float*)d_in[10];
    const float* ab2       = (const float*)d_in[11];
    const float* fw1       = (const float*)d_in[12];
    const float* fb1       = (const float*)d_in[13];
    const float* fw2       = (const float*)d_in[14];
    const float* fb2       = (const float*)d_in[15];
    const float* fw3       = (const float*)d_in[16];
    const float* fb3       = (const float*)d_in[17];
    float* out = (float*)d_out;

    // ---- ws layout (bytes from base) ----
    char* base = (char*)d_ws;
    __bf16* w1a    = (__bf16*)(base + 0);        // 4096 B
    __bf16* w2a    = (__bf16*)(base + 4096);     // 8192 B
    __bf16* w3ta   = (__bf16*)(base + 12288);    // 61440 B
    float*  b3t    = (float*)(base + 73728);     // 1920 B -> ends 75648
    int* cnt_dst   = (int*)(base + 75648);       // 25008*4 -> 175680
    int* cnt_t     = (int*)(base + 175680);      // 64 B -> 175744 (memset covers to 175808)
    int4* tlist4   = (int4*)(base + 175808);     // 460800*16 = 7372800 -> 7548608
    _Float16* payload = (_Float16*)(base + 7548672);  // 1.6M rows * 128 B = 204.8 MB

    hipMemsetAsync(cnt_dst, 0, 100160, stream);        // cnt_dst + cnt_t
    prep_count_k<<<64 + (NE + 255) / 256, 256, 0, stream>>>(
        emb_table, aw1, ab1, aw2, ab2, fw1, fb1, fw2, fw3, fb3,
        w1a, w2a, w3ta, b3t, esrc, edst, A, pos, shifts, cell, batch,
        cnt_dst, cnt_t, tlist4);
    edge_k<<<10 * BPT, 64, 0, stream>>>(tlist4, cnt_t, w1a, w2a, w3ta, fb2, b3t, payload);
    gather_k<<<NN, 256, 0, stream>>>(cnt_dst, payload, out);
}

// Round 10
// 180.110 us; speedup vs baseline: 1.3537x; 1.3537x over previous
//
#include <hip/hip_runtime.h>
#include <math.h>

#define NN 25000
#define NE 400000
#define TD 416
#define TCAP 46080             // per-type bucket capacity (64-aligned, mean 40000 + 7.8 sigma)
#define NROWS (TCAP * 10)      // 460800 bucket slots
#define PLH 64                 // payload row stride in halves (128 B = 2 lines)
#define NCAP 64                // fixed payload rows per node (deg ~Poisson(16); P(>=64) ~ 1e-20)
#define GROWS 32
#define BPT (TCAP / 64)        // 720 one-wave blocks per type

typedef __attribute__((ext_vector_type(8))) __bf16 bf16x8;
typedef __attribute__((ext_vector_type(4))) _Float16 f16x4;
typedef __attribute__((ext_vector_type(4))) float f32x4;

__device__ __forceinline__ float silu_f(float x) {
    // fast rcp: v_rcp_f32 (1 inst) instead of IEEE div sequence (~11 insts).
    return x * __builtin_amdgcn_rcpf(1.0f + __expf(-x));
}

// ---------- fused: [blocks 0..63] weight prep, [blocks 64..] count + geometry + bucket ----------
// Geometry computed HERE where e is linear (edst/esrc/shifts streamed; pos gathers are
// L2-resident 300KB). Bucket record = {vx,vy,vz, pd} so edge_k has zero random gathers.
__global__ __launch_bounds__(256) void prep_count_k(
    const float* __restrict__ emb_table,
    const float* __restrict__ aw1, const float* __restrict__ ab1,
    const float* __restrict__ aw2, const float* __restrict__ ab2,
    const float* __restrict__ fw1, const float* __restrict__ fb1,
    const float* __restrict__ fw2,
    const float* __restrict__ fw3, const float* __restrict__ fb3,
    __bf16* __restrict__ w1a, __bf16* __restrict__ w2a,
    __bf16* __restrict__ w3ta, float* __restrict__ b3t,
    const int* __restrict__ esrc, const int* __restrict__ edst,
    const int* __restrict__ A,
    const float* __restrict__ pos, const float* __restrict__ shifts,
    const float* __restrict__ cell, const int* __restrict__ batch,
    int* __restrict__ cnt_dst, int* __restrict__ cnt_t,
    int4* __restrict__ tlist4) {
    const int tid = threadIdx.x;
    if (blockIdx.x < 64) {
        __shared__ float s_ai[80];
        if (tid < 10) {
            float acc[8];
#pragma unroll
            for (int o = 0; o < 8; ++o) acc[o] = ab2[o];
            for (int j = 0; j < 64; ++j) {
                float h = ab1[j];
#pragma unroll
                for (int i = 0; i < 16; ++i) h += emb_table[tid * 16 + i] * aw1[i * 64 + j];
                h = silu_f(h);
#pragma unroll
                for (int o = 0; o < 8; ++o) acc[o] += h * aw2[j * 8 + o];
            }
#pragma unroll
            for (int o = 0; o < 8; ++o) s_ai[tid * 8 + o] = acc[o];
        }
        __syncthreads();
        for (int i = blockIdx.x * 256 + tid; i < 37344; i += 64 * 256) {
            if (i < 2048) {
                int m = i >> 9, r = i & 511, lane = r >> 3, j = r & 7;
                int k = (lane >> 4) * 8 + j, ch = m * 16 + (lane & 15);
                float v = (k < 8) ? fw1[k * 64 + ch] : ((k == 8) ? fb1[ch] : 0.0f);
                w1a[i] = (__bf16)v;
            } else if (i < 6144) {
                int q = i - 2048;
                int mk = q >> 9, lane = (q >> 3) & 63, j = q & 7;
                int m = mk >> 1, kt = mk & 1;
                int k = kt * 32 + (lane >> 4) * 8 + j, ch = m * 16 + (lane & 15);
                w2a[q] = (__bf16)fw2[k * 64 + ch];
            } else if (i < 36864) {
                int q = i - 6144;
                int tmk = q >> 9, lane = (q >> 3) & 63, j = q & 7;
                int kt = tmk & 1, tm = tmk >> 1;
                int t = tm / 3, m = tm - t * 3;
                int k = kt * 32 + (lane >> 4) * 8 + j, ch = m * 16 + (lane & 15);
                int l = ch >> 4, o = ch & 15;
                float s = 0.f;
#pragma unroll
                for (int c = 0; c < 8; ++c)
                    s += s_ai[t * 8 + c] * fw3[k * 384 + l * 128 + c * 16 + o];
                w3ta[q] = (__bf16)s;
            } else {
                int q2 = i - 36864;
                int t = q2 / 48, ch = q2 - t * 48;
                int l = ch >> 4, o = ch & 15;
                float s = 0.f;
#pragma unroll
                for (int c = 0; c < 8; ++c)
                    s += s_ai[t * 8 + c] * fb3[l * 128 + c * 16 + o];
                b3t[q2] = s;
            }
        }
    } else {
        __shared__ int lcnt[10];
        __shared__ int gbase[10];
        if (tid < 10) lcnt[tid] = 0;
        __syncthreads();
        int e = (blockIdx.x - 64) * 256 + tid;
        int t = 0, lr = 0;
        int4 rec;
        bool valid = e < NE;
        if (valid) {
            const int dst = edst[e];                     // linear
            const int src = esrc[e];                     // linear
            int rank = atomicAdd(&cnt_dst[dst], 1);      // rank within dst node (< NCAP)
            t = A[src];
            lr = atomicAdd(&lcnt[t], 1);
            // geometry (shifts linear; pos gathers hit L2: 300KB array)
            const int b = batch[src];
            const float* cb = cell + b * 9;
            const float sh0 = shifts[e * 3 + 0], sh1 = shifts[e * 3 + 1], sh2 = shifts[e * 3 + 2];
            float vx = pos[dst * 3 + 0] - pos[src * 3 + 0] + sh0 * cb[0] + sh1 * cb[3] + sh2 * cb[6];
            float vy = pos[dst * 3 + 1] - pos[src * 3 + 1] + sh0 * cb[1] + sh1 * cb[4] + sh2 * cb[7];
            float vz = pos[dst * 3 + 2] - pos[src * 3 + 2] + sh0 * cb[2] + sh1 * cb[5] + sh2 * cb[8];
            rec.x = __float_as_int(vx);
            rec.y = __float_as_int(vy);
            rec.z = __float_as_int(vz);
            rec.w = (dst << 6) | rank;                   // pd = dst*NCAP + rank
        }
        __syncthreads();
        if (tid < 10) gbase[tid] = atomicAdd(&cnt_t[tid], lcnt[tid]);
        __syncthreads();
        if (valid) tlist4[t * TCAP + gbase[t] + lr] = rec;
    }
}

// ---------- edge kernel: 1 wave = 64 edges; 3 MFMA GEMMs; single streamed 16B input ----------
// Zero random gathers: the bucket record carries vec + payload row. Weights register-resident.
// 1-wave WGs: __syncthreads compiles to bare waitcnts (verified optimum vs r6/r7/r8 variants).
__global__ __launch_bounds__(64) void edge_k(
    const int4* __restrict__ tlist4, const int* __restrict__ cnt_t,
    const __bf16* __restrict__ w1a, const __bf16* __restrict__ w2a,
    const __bf16* __restrict__ w3ta,
    const float* __restrict__ fb2, const float* __restrict__ b3t,
    _Float16* __restrict__ payload) {
    __shared__ __bf16 embuf[64 * 8];                   // 1 KB (8 real basis values/edge)
    __shared__ __bf16 h1buf[16 * 72];                  // 2.3 KB
    __shared__ __bf16 h2buf[16 * 72];                  // 2.3 KB
    __shared__ int pbuf[64];                           // payload row index per wave slot
    const int lane = threadIdx.x;
    const int t_blk = blockIdx.x / BPT;
    const int local = (blockIdx.x - t_blk * BPT) * 64;
    const int nval = cnt_t[t_blk];
    if (local >= nval) return;                         // fully-padded block

    const int idx = min(local + lane, nval - 1);       // pad lanes dup last edge (benign)
    const int4 rec = tlist4[t_blk * TCAP + idx];       // ONE streamed 16B load = whole input
    const float vx = __int_as_float(rec.x);
    const float vy = __int_as_float(rec.y);
    const float vz = __int_as_float(rec.z);
    const int pd = rec.w;
    pbuf[lane] = pd;

    const float l2 = vx * vx + vy * vy + vz * vz + 1e-12f;
    const float il = __builtin_amdgcn_rsqf(l2);        // v_rsq_f32
    const float len = l2 * il;
    // u + zero pad -> bytes 96..127 of the row fully written (no RMW fetch)
    {
        const uint4 z4 = {0u, 0u, 0u, 0u};
        union { float f[4]; uint4 u; } uu;
        uu.f[0] = vx * il; uu.f[1] = vy * il; uu.f[2] = vz * il; uu.f[3] = 0.f;
        *(uint4*)(payload + (size_t)pd * PLH + 48) = uu.u;
        *(uint4*)(payload + (size_t)pd * PLH + 56) = z4;
    }

    // radial basis row (8 real values; constant rows handled in-register via bone)
    bf16x8 er0;
#pragma unroll
    for (int k = 0; k < 8; ++k) {
        float d = (len - (5.0f * (float)(k + 1) / 9.0f)) * 1.8f;
        er0[k] = (__bf16)(__expf(-d * d) * 2.525381361380528f);  // sqrt(8)/1.12
    }
    *(bf16x8*)&embuf[lane * 8] = er0;

    // ---- weights + biases: block-resident in VGPRs ----
    bf16x8 a1[4], a2[8], a3[6];
#pragma unroll
    for (int m = 0; m < 4; ++m) a1[m] = *(const bf16x8*)(w1a + (m * 64 + lane) * 8);
#pragma unroll
    for (int i = 0; i < 8; ++i) a2[i] = *(const bf16x8*)(w2a + (i * 64 + lane) * 8);
#pragma unroll
    for (int i = 0; i < 6; ++i)
        a3[i] = *(const bf16x8*)(w3ta + ((size_t)(t_blk * 6 + i) * 64 + lane) * 8);
    const int q = lane >> 4;
    const int qr = q * 4;
    const int q8 = q * 8;
    const int colrow = lane & 15;
    f32x4 bias2[4], bias3[3];
#pragma unroll
    for (int m = 0; m < 4; ++m) bias2[m] = *(const f32x4*)(fb2 + m * 16 + qr);
#pragma unroll
    for (int m = 0; m < 3; ++m) bias3[m] = *(const f32x4*)(b3t + t_blk * 48 + m * 16 + qr);

    bf16x8 bone = {};
    bone[0] = (__bf16)1.0f;   // k=8 bias row; k>8 rows multiply zero weights
    __syncthreads();          // covers embuf + pbuf

    const float SC = (float)NN / (float)NE;  // 1/16
#pragma unroll 1
    for (int n = 0; n < 4; ++n) {
        const int erow = n * 16 + colrow;
        // GEMM1: h1 = silu(emb @ W1 + b1); B-quadrants 1..3 are constants
        bf16x8 bd = *(bf16x8*)&embuf[erow * 8];
        bf16x8 b1 = (q == 0) ? bd : bone;
#pragma unroll
        for (int m = 0; m < 4; ++m) {
            f32x4 c = {0.f, 0.f, 0.f, 0.f};
            c = __builtin_amdgcn_mfma_f32_16x16x32_bf16(a1[m], b1, c, 0, 0, 0);
            __bf16 hp[4];
#pragma unroll
            for (int r = 0; r < 4; ++r) hp[r] = (__bf16)silu_f(c[r]);
            *(uint2*)&h1buf[colrow * 72 + m * 16 + qr] = *(uint2*)hp;
        }
        __syncthreads();
        // GEMM2: h2 = silu(h1 @ W2 + b2)
        bf16x8 b20 = *(bf16x8*)&h1buf[colrow * 72 + q8];
        bf16x8 b21 = *(bf16x8*)&h1buf[colrow * 72 + 32 + q8];
#pragma unroll
        for (int m = 0; m < 4; ++m) {
            f32x4 c = bias2[m];
            c = __builtin_amdgcn_mfma_f32_16x16x32_bf16(a2[m * 2 + 0], b20, c, 0, 0, 0);
            c = __builtin_amdgcn_mfma_f32_16x16x32_bf16(a2[m * 2 + 1], b21, c, 0, 0, 0);
            __bf16 hp[4];
#pragma unroll
            for (int r = 0; r < 4; ++r) hp[r] = (__bf16)silu_f(c[r]);
            *(uint2*)&h2buf[colrow * 72 + m * 16 + qr] = *(uint2*)hp;
        }
        __syncthreads();
        // GEMM3: s = (h2 @ W3t + b3t) * SC -> fp16 straight to global payload row
        const int prow = pbuf[erow];
        bf16x8 b30 = *(bf16x8*)&h2buf[colrow * 72 + q8];
        bf16x8 b31 = *(bf16x8*)&h2buf[colrow * 72 + 32 + q8];
#pragma unroll
        for (int m = 0; m < 3; ++m) {
            f32x4 c = bias3[m];
            c = __builtin_amdgcn_mfma_f32_16x16x32_bf16(a3[m * 2 + 0], b30, c, 0, 0, 0);
            c = __builtin_amdgcn_mfma_f32_16x16x32_bf16(a3[m * 2 + 1], b31, c, 0, 0, 0);
            f16x4 hp;
#pragma unroll
            for (int r = 0; r < 4; ++r) hp[r] = (_Float16)(c[r] * SC);
            *(f16x4*)(payload + (size_t)prow * PLH + m * 16 + qr) = hp;
        }
        // no barrier: next iter's h1buf write is fenced by the GEMM1-end barrier,
        // whose lgkmcnt(0) drain also retires this iter's h2buf reads.
    }
}

// ---------- gather: node's fixed-cap payload rows -> factor-table expansion -> out ----------
// (r5 structure verbatim; only change: staging skips the dead 8th uint4 per row —
// bytes 112..127 are never read, saving 1/8 of gather's payload fetch + VMEM issue.)
__global__ __launch_bounds__(256) void gather_k(const int* __restrict__ cnt_dst,
                                                const _Float16* __restrict__ payload,
                                                float* __restrict__ out) {
    __shared__ __align__(16) _Float16 sp_s[GROWS][72];
    __shared__ float sfac[GROWS][16];
    const int n = blockIdx.x;
    const int tid = threadIdx.x;
    const int lo = n * NCAP;
    const int cnt = cnt_dst[n];
    int voff = 0, foff = 0;
    if (tid < 16) { voff = tid; foff = 0; }
    else if (tid < 64) { int q = tid - 16; voff = 16 + q / 3; foff = 1 + q % 3; }
    else if (tid < 208) { int q = tid - 64; voff = 32 + q / 9; foff = 4 + q % 9; }
    float acc = 0.f;
    for (int p0 = 0; p0 < cnt; p0 += GROWS) {
        const int m = min(GROWS, cnt - p0);
        // payload rows [lo+p0, lo+p0+m) are contiguous: coalesced streaming load.
        // 7 x uint4 per row = bytes 0..111 (values + u); bytes 112..127 are dead pad.
        if (tid < m * 8 && (tid & 7) != 7) {
            int r = tid >> 3, q = tid & 7;
            ((uint4*)&sp_s[r][0])[q] = ((const uint4*)(payload + (size_t)(lo + p0 + r) * PLH))[q];
        }
        __syncthreads();
        for (int idx = tid; idx < m * 16; idx += 256) {
            int r = idx >> 4, f = idx & 15;
            if (f < 13) {
                const float* uf = (const float*)&sp_s[r][48];
                float v;
                if (f == 0) v = 1.0f;
                else if (f < 4) v = uf[f - 1];
                else { int g = f - 4; v = uf[g / 3] * uf[g % 3]; }
                sfac[r][f] = v;
            }
        }
        __syncthreads();
        if (tid < 208)
            for (int r = 0; r < m; ++r)
                acc += (float)sp_s[r][voff] * sfac[r][foff];
        __syncthreads();
    }
    if (tid < 208) {
        out[(size_t)n * TD + tid] = acc;
        out[(size_t)n * TD + 208 + tid] = 0.f;
    }
}

extern "C" void kernel_launch(void* const* d_in, const int* in_sizes, int n_in,
                              void* d_out, int out_size, void* d_ws, size_t ws_size,
                              hipStream_t stream) {
    const float* pos       = (const float*)d_in[0];
    const int*   A         = (const int*)d_in[1];
    const int*   batch     = (const int*)d_in[2];
    const int*   esrc      = (const int*)d_in[3];
    const int*   edst      = (const int*)d_in[4];
    const float* shifts    = (const float*)d_in[5];
    const float* cell      = (const float*)d_in[6];
    const float* emb_table = (const float*)d_in[7];
    const float* aw1       = (const float*)d_in[8];
    const float* ab1       = (const float*)d_in[9];
    const float* aw2       = (const float*)d_in[10];
    const float* ab2       = (const float*)d_in[11];
    const float* fw1       = (const float*)d_in[12];
    const float* fb1       = (const float*)d_in[13];
    const float* fw2       = (const float*)d_in[14];
    const float* fb2       = (const float*)d_in[15];
    const float* fw3       = (const float*)d_in[16];
    const float* fb3       = (const float*)d_in[17];
    float* out = (float*)d_out;

    // ---- ws layout (bytes from base) ----
    char* base = (char*)d_ws;
    __bf16* w1a    = (__bf16*)(base + 0);        // 4096 B
    __bf16* w2a    = (__bf16*)(base + 4096);     // 8192 B
    __bf16* w3ta   = (__bf16*)(base + 12288);    // 61440 B
    float*  b3t    = (float*)(base + 73728);     // 1920 B -> ends 75648
    int* cnt_dst   = (int*)(base + 75648);       // 25008*4 -> 175680
    int* cnt_t     = (int*)(base + 175680);      // 64 B -> 175744 (memset covers to 175808)
    int4* tlist4   = (int4*)(base + 175808);     // 460800*16 = 7372800 -> 7548608
    _Float16* payload = (_Float16*)(base + 7548672);  // 1.6M rows * 128 B = 204.8 MB

    hipMemsetAsync(cnt_dst, 0, 100160, stream);        // cnt_dst + cnt_t
    prep_count_k<<<64 + (NE + 255) / 256, 256, 0, stream>>>(
        emb_table, aw1, ab1, aw2, ab2, fw1, fb1, fw2, fw3, fb3,
        w1a, w2a, w3ta, b3t, esrc, edst, A, pos, shifts, cell, batch,
        cnt_dst, cnt_t, tlist4);
    edge_k<<<10 * BPT, 64, 0, stream>>>(tlist4, cnt_t, w1a, w2a, w3ta, fb2, b3t, payload);
    gather_k<<<NN, 256, 0, stream>>>(cnt_dst, payload, out);
}